// Round 1
// baseline (2121.395 us; speedup 1.0000x reference)
//
#include <hip/hip_runtime.h>
#include <cstdint>
#include <cstddef>

// Problem dims
#define BB 8
#define SS 256
#define DP 16
#define HH 256
#define NHEAD 8
#define DHEAD 32
#define NLAYER 3

__device__ __forceinline__ float sigf(float x) { return 1.0f / (1.0f + __expf(-x)); }
__device__ __forceinline__ float tanhfast(float x) {
  float e = __expf(-2.0f * fabsf(x));
  float t = (1.0f - e) / (1.0f + e);
  return copysignf(t, x);
}
__device__ __forceinline__ unsigned short f2bf(float f) {
  unsigned int u = __float_as_uint(f);
  u = (u + 0x7fffu + ((u >> 16) & 1u)) >> 16;
  return (unsigned short)u;
}
__device__ __forceinline__ float bflo(unsigned int u) { return __uint_as_float(u << 16); }
__device__ __forceinline__ float bfhi(unsigned int u) { return __uint_as_float(u & 0xffff0000u); }

// ---------------- part encoder: x[:, :128]=MLP(parts), [128:192]=pos, [192:256]=0 ----
__global__ void part_encoder(const float* __restrict__ parts, const float* __restrict__ Wpe1,
                             const float* __restrict__ bpe1, const float* __restrict__ Wpe2,
                             const float* __restrict__ bpe2, const float* __restrict__ pos,
                             float* __restrict__ x) {
  __shared__ float prow[16];
  __shared__ float pe1[128];
  int row = blockIdx.x;          // b*256 + s
  int s = row & 255;
  int tid = threadIdx.x;         // 128 threads
  if (tid < 16) prow[tid] = parts[row * 16 + tid];
  __syncthreads();
  float a = bpe1[tid];
#pragma unroll
  for (int k = 0; k < 16; ++k) a = fmaf(prow[k], Wpe1[tid * 16 + k], a);
  pe1[tid] = fmaxf(a, 0.0f);
  __syncthreads();
  float a2 = bpe2[tid];
  for (int k = 0; k < 128; ++k) a2 = fmaf(pe1[k], Wpe2[tid * 128 + k], a2);
  x[(size_t)row * 256 + tid] = a2;
  if (tid < 64) {
    x[(size_t)row * 256 + 128 + tid] = pos[s * 64 + tid];
    x[(size_t)row * 256 + 192 + tid] = 0.0f;
  }
}

// ---------------- generic f32 GEMM: C[m,n] = act(A[m,:]·Wt[n,:] + b1[n] (+ b2[n])) ----
// A [M,K] row-major, Wt [N,K] row-major. Tile 64x64, 256 thr, 4x4/thread, KT=16.
template <int ACT>
__global__ __launch_bounds__(256) void gemm_f32(
    const float* __restrict__ A, const float* __restrict__ Wt,
    const float* __restrict__ bias1, const float* __restrict__ bias2,
    float* __restrict__ C, int N, int K) {
  __shared__ float As[16][68];
  __shared__ float Ws[16][68];
  int tid = threadIdx.x;
  int tx = tid & 15, ty = tid >> 4;
  int m0 = blockIdx.y * 64, n0 = blockIdx.x * 64;
  int mm = tid >> 2, c4 = (tid & 3) * 4;
  float acc[4][4] = {};
  for (int k0 = 0; k0 < K; k0 += 16) {
    float4 av = *(const float4*)&A[(size_t)(m0 + mm) * K + k0 + c4];
    float4 wv = *(const float4*)&Wt[(size_t)(n0 + mm) * K + k0 + c4];
    As[c4 + 0][mm] = av.x; As[c4 + 1][mm] = av.y; As[c4 + 2][mm] = av.z; As[c4 + 3][mm] = av.w;
    Ws[c4 + 0][mm] = wv.x; Ws[c4 + 1][mm] = wv.y; Ws[c4 + 2][mm] = wv.z; Ws[c4 + 3][mm] = wv.w;
    __syncthreads();
#pragma unroll
    for (int kk = 0; kk < 16; ++kk) {
      float4 a = *(const float4*)&As[kk][ty * 4];
      float4 w = *(const float4*)&Ws[kk][tx * 4];
      float aa[4] = {a.x, a.y, a.z, a.w};
      float ww[4] = {w.x, w.y, w.z, w.w};
#pragma unroll
      for (int i = 0; i < 4; ++i)
#pragma unroll
        for (int j = 0; j < 4; ++j) acc[i][j] = fmaf(aa[i], ww[j], acc[i][j]);
    }
    __syncthreads();
  }
#pragma unroll
  for (int i = 0; i < 4; ++i) {
    int m = m0 + ty * 4 + i;
    float4 o4;
    float* po = (float*)&o4;
#pragma unroll
    for (int j = 0; j < 4; ++j) {
      int n = n0 + tx * 4 + j;
      float v = acc[i][j] + bias1[n] + (bias2 ? bias2[n] : 0.0f);
      if (ACT == 1) v = fmaxf(v, 0.0f);
      po[j] = v;
    }
    *(float4*)&C[(size_t)m * N + n0 + tx * 4] = o4;
  }
}

// ---------------- attention: per (qtile, head, batch) block ----------------
__global__ void attn_kernel(const float* __restrict__ qkv, float* __restrict__ attout) {
  extern __shared__ float sm[];
  float* kl = sm;                        // [256][33]
  float* ql = sm + 256 * 33;             // [32][33]
  float* sc = sm + 256 * 33 + 32 * 33;   // [32][257]
  int qt = blockIdx.x, h = blockIdx.y, b = blockIdx.z;
  int tid = threadIdx.x;  // 256
  {
    int j = tid;
    const float* src = qkv + (size_t)(b * 256 + j) * 768 + 256 + h * 32;
#pragma unroll
    for (int d = 0; d < 32; d += 4) {
      float4 v = *(const float4*)(src + d);
      kl[j * 33 + d] = v.x; kl[j * 33 + d + 1] = v.y; kl[j * 33 + d + 2] = v.z; kl[j * 33 + d + 3] = v.w;
    }
  }
  {
    int i = tid >> 3, d4 = (tid & 7) * 4;
    const float* src = qkv + (size_t)(b * 256 + qt * 32 + i) * 768 + h * 32;
    float4 v = *(const float4*)(src + d4);
    ql[i * 33 + d4] = v.x; ql[i * 33 + d4 + 1] = v.y; ql[i * 33 + d4 + 2] = v.z; ql[i * 33 + d4 + 3] = v.w;
  }
  __syncthreads();
  int i = tid >> 3, c = tid & 7;
  const float scale = 0.17677669529663687f;  // 1/sqrt(32)
  float sv[32];
  float mx = -1e30f;
  for (int jj = 0; jj < 32; ++jj) {
    int j = jj * 8 + c;
    float s = 0.0f;
#pragma unroll
    for (int d = 0; d < 32; ++d) s = fmaf(ql[i * 33 + d], kl[j * 33 + d], s);
    s *= scale;
    sv[jj] = s;
    mx = fmaxf(mx, s);
  }
  mx = fmaxf(mx, __shfl_xor(mx, 1));
  mx = fmaxf(mx, __shfl_xor(mx, 2));
  mx = fmaxf(mx, __shfl_xor(mx, 4));
  float sum = 0.0f;
  for (int jj = 0; jj < 32; ++jj) {
    float p = __expf(sv[jj] - mx);
    sc[i * 257 + jj * 8 + c] = p;
    sum += p;
  }
  sum += __shfl_xor(sum, 1);
  sum += __shfl_xor(sum, 2);
  sum += __shfl_xor(sum, 4);
  float inv = 1.0f / sum;
  __syncthreads();
  float a0 = 0, a1 = 0, a2 = 0, a3 = 0;
  int d0 = c * 4;
  const float* vbase = qkv + 512 + h * 32 + d0;
  for (int j = 0; j < 256; ++j) {
    float p = sc[i * 257 + j];
    float4 v = *(const float4*)(vbase + (size_t)(b * 256 + j) * 768);
    a0 = fmaf(p, v.x, a0); a1 = fmaf(p, v.y, a1); a2 = fmaf(p, v.z, a2); a3 = fmaf(p, v.w, a3);
  }
  int orow = b * 256 + qt * 32 + i;
  float4 o4 = {a0 * inv, a1 * inv, a2 * inv, a3 * inv};
  *(float4*)&attout[(size_t)orow * 256 + h * 32 + d0] = o4;
}

// ---------------- LayerNorm(x + o) in place on x ----------------
__global__ void ln_residual(float* __restrict__ x, const float* __restrict__ o,
                            const float* __restrict__ g, const float* __restrict__ bt) {
  int row = blockIdx.x, tid = threadIdx.x;  // 256 threads
  float e = x[(size_t)row * 256 + tid] + o[(size_t)row * 256 + tid];
  float s = e, q = e * e;
#pragma unroll
  for (int off = 32; off >= 1; off >>= 1) {
    s += __shfl_xor(s, off);
    q += __shfl_xor(q, off);
  }
  __shared__ float ps[4], pq[4];
  int wid = tid >> 6, lane = tid & 63;
  if (lane == 0) { ps[wid] = s; pq[wid] = q; }
  __syncthreads();
  float St = ps[0] + ps[1] + ps[2] + ps[3];
  float Qt = pq[0] + pq[1] + pq[2] + pq[3];
  float mean = St * (1.0f / 256.0f);
  float var = Qt * (1.0f / 256.0f) - mean * mean;
  float y = (e - mean) * rsqrtf(var + 1e-5f) * g[tid] + bt[tid];
  x[(size_t)row * 256 + tid] = y;
}

// ---------------- gather dec_in rows [T,B,H]: row t*8+b ----------------
__global__ void gather_dec_in(const float* __restrict__ enc, const int* __restrict__ ts,
                              float* __restrict__ dec_in) {
  int bx = blockIdx.x;     // t*8 + b
  int t = bx >> 3, b = bx & 7;
  int tid = threadIdx.x;   // 64
  float4 v = {0.0f, 0.0f, 0.0f, 0.0f};
  if (t > 0) {
    int sidx = ts[b * 256 + t - 1];
    v = *(const float4*)&enc[((size_t)(b * 256 + sidx)) * 256 + tid * 4];
  }
  *(float4*)&dec_in[(size_t)bx * 256 + tid * 4] = v;
}

// ---------------- LSTM scan: 32 blocks = (b, s4), cross-block sync per step --------
__global__ __launch_bounds__(512) void lstm_scan(
    const float* __restrict__ Xw, const float* __restrict__ Whh,
    float* __restrict__ hglob, unsigned int* __restrict__ cnt,
    float* __restrict__ dec_out) {
  extern __shared__ char smem[];
  unsigned short* whh = (unsigned short*)smem;       // [256][264] bf16
  float* h_lds = (float*)(smem + 256 * 264 * 2);     // [256]
  float* gp = h_lds + 256;                           // [2][256]
  int bx = blockIdx.x;
  int b = bx >> 2, s4 = bx & 3;
  int tid = threadIdx.x;        // 512
  int lr = tid >> 1, half = tid & 1;
  int gi = lr >> 6, jj = lr & 63;
  int Rg = gi * 256 + s4 * 64 + jj;   // global gate row in [0,1024)
  {   // stage Whh slice as bf16
    const float* src = Whh + (size_t)Rg * 256 + half * 128;
    unsigned short* dst = whh + lr * 264 + half * 128;
    for (int k = 0; k < 128; k += 4) {
      float4 v = *(const float4*)(src + k);
      dst[k] = f2bf(v.x); dst[k + 1] = f2bf(v.y); dst[k + 2] = f2bf(v.z); dst[k + 3] = f2bf(v.w);
    }
  }
  if (tid < 256) h_lds[tid] = 0.0f;
  float c_reg = 0.0f;
  __syncthreads();
  unsigned int target = 0;
  for (int t = 0; t < 256; ++t) {
    float xw = (half == 0) ? Xw[(size_t)(t * 8 + b) * 1024 + Rg] : 0.0f;
    const unsigned short* wr = whh + lr * 264 + half * 128;
    const float* hr = h_lds + half * 128;
    float acc = 0.0f;
#pragma unroll
    for (int k = 0; k < 128; k += 8) {
      uint4 w8 = *(const uint4*)(wr + k);
      float4 h0 = *(const float4*)(hr + k);
      float4 h1 = *(const float4*)(hr + k + 4);
      acc = fmaf(bflo(w8.x), h0.x, acc);
      acc = fmaf(bfhi(w8.x), h0.y, acc);
      acc = fmaf(bflo(w8.y), h0.z, acc);
      acc = fmaf(bfhi(w8.y), h0.w, acc);
      acc = fmaf(bflo(w8.z), h1.x, acc);
      acc = fmaf(bfhi(w8.z), h1.y, acc);
      acc = fmaf(bflo(w8.w), h1.z, acc);
      acc = fmaf(bfhi(w8.w), h1.w, acc);
    }
    gp[half * 256 + lr] = acc + xw;
    __syncthreads();
    if (tid < 64) {
      int j = tid;
      float iv = gp[j] + gp[256 + j];
      float fv = gp[64 + j] + gp[320 + j];
      float gv = gp[128 + j] + gp[384 + j];
      float ov = gp[192 + j] + gp[448 + j];
      c_reg = sigf(fv) * c_reg + sigf(iv) * tanhfast(gv);
      float hv = sigf(ov) * tanhfast(c_reg);
      int hx = s4 * 64 + j;
      hglob[(size_t)(t & 1) * 2048 + b * 256 + hx] = hv;
      dec_out[((size_t)(b * 256 + t)) * 256 + hx] = hv;
    }
    __threadfence();
    __syncthreads();
    target += 4;
    if (tid == 0) {
      atomicAdd(&cnt[b], 1u);
      while (__hip_atomic_load(&cnt[b], __ATOMIC_ACQUIRE, __HIP_MEMORY_SCOPE_AGENT) < target) {
        __builtin_amdgcn_s_sleep(2);
      }
    }
    __syncthreads();
    if (tid < 256) {
      h_lds[tid] = __hip_atomic_load(&hglob[(size_t)(t & 1) * 2048 + b * 256 + tid],
                                     __ATOMIC_RELAXED, __HIP_MEMORY_SCOPE_AGENT);
    }
    __syncthreads();
  }
}

// ---------------- pen transpose: penT[b][h][i] = pen[(b*256+i)][h] ----------------
__global__ void transpose_pen(const float* __restrict__ pen, float* __restrict__ penT) {
  int bx = blockIdx.x;  // b*256 + h
  int b = bx >> 8, h = bx & 255;
  int i = threadIdx.x;  // 256
  penT[(size_t)bx * 256 + i] = pen[((size_t)(b * 256 + i)) * 256 + h];
}

// ---------------- pointer logits ----------------
__global__ void pointer_kernel(const float* __restrict__ pd, const float* __restrict__ penT,
                               const float* __restrict__ vptr, float* __restrict__ out) {
  __shared__ float pdr[256];
  __shared__ float vl[256];
  int bx = blockIdx.x;  // b*256 + t
  int b = bx >> 8;
  int tid = threadIdx.x;  // 256; tid = i (source index)
  pdr[tid] = pd[(size_t)bx * 256 + tid];
  vl[tid] = vptr[tid];
  __syncthreads();
  const float* pT = penT + (size_t)b * 256 * 256;
  float acc = 0.0f;
  for (int h = 0; h < 256; ++h) {
    acc = fmaf(vl[h], tanhfast(pdr[h] + pT[(size_t)h * 256 + tid]), acc);
  }
  out[(size_t)bx * 256 + tid] = acc;
}

extern "C" void kernel_launch(void* const* d_in, const int* in_sizes, int n_in,
                              void* d_out, int out_size, void* d_ws, size_t ws_size,
                              hipStream_t stream) {
  const float* parts = (const float*)d_in[0];
  const int* ts = (const int*)d_in[1];
  const float* Wpe1 = (const float*)d_in[2];
  const float* bpe1 = (const float*)d_in[3];
  const float* Wpe2 = (const float*)d_in[4];
  const float* bpe2 = (const float*)d_in[5];
  const float* pos = (const float*)d_in[6];
  const float* Wqkv = (const float*)d_in[7];
  const float* bqkv = (const float*)d_in[8];
  const float* Wo = (const float*)d_in[9];
  const float* bo = (const float*)d_in[10];
  const float* ln1g = (const float*)d_in[11];
  const float* ln1b = (const float*)d_in[12];
  const float* W1f = (const float*)d_in[13];
  const float* b1f = (const float*)d_in[14];
  const float* W2f = (const float*)d_in[15];
  const float* b2f = (const float*)d_in[16];
  const float* ln2g = (const float*)d_in[17];
  const float* ln2b = (const float*)d_in[18];
  const float* Wih = (const float*)d_in[19];
  const float* Whh = (const float*)d_in[20];
  const float* bih = (const float*)d_in[21];
  const float* bhh = (const float*)d_in[22];
  const float* Wp = (const float*)d_in[23];
  const float* bp = (const float*)d_in[24];
  const float* vptr = (const float*)d_in[25];
  float* out = (float*)d_out;

  // workspace layout (floats); regions reused across phases (lifetimes disjoint)
  float* W = (float*)d_ws;
  float* xbuf = W;                    // [2048,256]  enc activations (live whole run)
  float* qkvb = W + 524288;           // [2048,768]
  float* attb = W + 2097152;          // [2048,256]
  float* obuf = W + 2621440;          // [2048,256]
  float* ffb  = W + 3145728;          // [2048,512]
  float* dec_in = obuf;               // reuse after encoder
  float* Xw = qkvb;                   // [2048,1024] spans qkvb+attb after encoder
  float* dec_out = ffb;               // [2048,256]
  float* pdb  = W + 3670016;          // [2048,256]
  float* penb = W + 4194304;          // [2048,256]
  float* penTb = W + 4718592;         // [2048,256]
  float* hg = W + 5242880;            // [2][8][256]
  unsigned int* cnt = (unsigned int*)(W + 5242880 + 4096);  // [8]

  const int attnLDS = (256 * 33 + 32 * 33 + 32 * 257) * 4;      // 70912 B
  const int scanLDS = 256 * 264 * 2 + (256 + 512) * 4;           // 138240 B
  hipFuncSetAttribute((const void*)attn_kernel, hipFuncAttributeMaxDynamicSharedMemorySize, attnLDS);
  hipFuncSetAttribute((const void*)lstm_scan, hipFuncAttributeMaxDynamicSharedMemorySize, scanLDS);

  part_encoder<<<2048, 128, 0, stream>>>(parts, Wpe1, bpe1, Wpe2, bpe2, pos, xbuf);
  for (int l = 0; l < 3; ++l) {
    gemm_f32<0><<<dim3(12, 32), 256, 0, stream>>>(xbuf, Wqkv + (size_t)l * 768 * 256,
                                                  bqkv + l * 768, nullptr, qkvb, 768, 256);
    attn_kernel<<<dim3(8, 8, 8), 256, attnLDS, stream>>>(qkvb, attb);
    gemm_f32<0><<<dim3(4, 32), 256, 0, stream>>>(attb, Wo + (size_t)l * 65536,
                                                 bo + l * 256, nullptr, obuf, 256, 256);
    ln_residual<<<2048, 256, 0, stream>>>(xbuf, obuf, ln1g + l * 256, ln1b + l * 256);
    gemm_f32<1><<<dim3(8, 32), 256, 0, stream>>>(xbuf, W1f + (size_t)l * 512 * 256,
                                                 b1f + l * 512, nullptr, ffb, 512, 256);
    gemm_f32<0><<<dim3(4, 32), 256, 0, stream>>>(ffb, W2f + (size_t)l * 256 * 512,
                                                 b2f + l * 256, nullptr, obuf, 256, 512);
    ln_residual<<<2048, 256, 0, stream>>>(xbuf, obuf, ln2g + l * 256, ln2b + l * 256);
  }
  gather_dec_in<<<2048, 64, 0, stream>>>(xbuf, ts, dec_in);
  gemm_f32<0><<<dim3(16, 32), 256, 0, stream>>>(dec_in, Wih, bih, bhh, Xw, 1024, 256);
  hipMemsetAsync(cnt, 0, 8 * sizeof(unsigned int), stream);
  lstm_scan<<<32, 512, scanLDS, stream>>>(Xw, Whh, hg, cnt, dec_out);
  gemm_f32<0><<<dim3(4, 32), 256, 0, stream>>>(dec_out, Wp, bp, nullptr, pdb, 256, 256);
  gemm_f32<0><<<dim3(4, 32), 256, 0, stream>>>(xbuf, Wp, bp, nullptr, penb, 256, 256);
  transpose_pen<<<2048, 256, 0, stream>>>(penb, penTb);
  pointer_kernel<<<2048, 256, 0, stream>>>(pdb, penTb, vptr, out);
}

// Round 2
// 1338.567 us; speedup vs baseline: 1.5848x; 1.5848x over previous
//
#include <hip/hip_runtime.h>
#include <cstdint>
#include <cstddef>

typedef _Float16 h2 __attribute__((ext_vector_type(2)));

__device__ __forceinline__ float sigf(float x) { return 1.0f / (1.0f + __expf(-x)); }
__device__ __forceinline__ float tanhfast(float x) {
  float e = __expf(-2.0f * fabsf(x));
  float t = (1.0f - e) / (1.0f + e);
  return copysignf(t, x);
}
__device__ __forceinline__ h2 cvt2(float a, float b) {
  h2 r; r.x = (_Float16)a; r.y = (_Float16)b; return r;
}

// ---------------- part encoder: x[:, :128]=MLP(parts), [128:192]=pos, [192:256]=0 ----
__global__ void part_encoder(const float* __restrict__ parts, const float* __restrict__ Wpe1,
                             const float* __restrict__ bpe1, const float* __restrict__ Wpe2,
                             const float* __restrict__ bpe2, const float* __restrict__ pos,
                             float* __restrict__ x) {
  __shared__ float prow[16];
  __shared__ float pe1[128];
  int row = blockIdx.x;          // b*256 + s
  int s = row & 255;
  int tid = threadIdx.x;         // 128 threads
  if (tid < 16) prow[tid] = parts[row * 16 + tid];
  __syncthreads();
  float a = bpe1[tid];
#pragma unroll
  for (int k = 0; k < 16; ++k) a = fmaf(prow[k], Wpe1[tid * 16 + k], a);
  pe1[tid] = fmaxf(a, 0.0f);
  __syncthreads();
  float a2 = bpe2[tid];
  for (int k = 0; k < 128; ++k) a2 = fmaf(pe1[k], Wpe2[tid * 128 + k], a2);
  x[(size_t)row * 256 + tid] = a2;
  if (tid < 64) {
    x[(size_t)row * 256 + 128 + tid] = pos[s * 64 + tid];
    x[(size_t)row * 256 + 192 + tid] = 0.0f;
  }
}

// ---------------- generic f32 GEMM: C[m,n] = act(A[m,:]·Wt[n,:] + b1[n] (+ b2[n])) ----
template <int ACT>
__global__ __launch_bounds__(256) void gemm_f32(
    const float* __restrict__ A, const float* __restrict__ Wt,
    const float* __restrict__ bias1, const float* __restrict__ bias2,
    float* __restrict__ C, int N, int K) {
  __shared__ float As[16][68];
  __shared__ float Ws[16][68];
  int tid = threadIdx.x;
  int tx = tid & 15, ty = tid >> 4;
  int m0 = blockIdx.y * 64, n0 = blockIdx.x * 64;
  int mm = tid >> 2, c4 = (tid & 3) * 4;
  float acc[4][4] = {};
  for (int k0 = 0; k0 < K; k0 += 16) {
    float4 av = *(const float4*)&A[(size_t)(m0 + mm) * K + k0 + c4];
    float4 wv = *(const float4*)&Wt[(size_t)(n0 + mm) * K + k0 + c4];
    As[c4 + 0][mm] = av.x; As[c4 + 1][mm] = av.y; As[c4 + 2][mm] = av.z; As[c4 + 3][mm] = av.w;
    Ws[c4 + 0][mm] = wv.x; Ws[c4 + 1][mm] = wv.y; Ws[c4 + 2][mm] = wv.z; Ws[c4 + 3][mm] = wv.w;
    __syncthreads();
#pragma unroll
    for (int kk = 0; kk < 16; ++kk) {
      float4 a = *(const float4*)&As[kk][ty * 4];
      float4 w = *(const float4*)&Ws[kk][tx * 4];
      float aa[4] = {a.x, a.y, a.z, a.w};
      float ww[4] = {w.x, w.y, w.z, w.w};
#pragma unroll
      for (int i = 0; i < 4; ++i)
#pragma unroll
        for (int j = 0; j < 4; ++j) acc[i][j] = fmaf(aa[i], ww[j], acc[i][j]);
    }
    __syncthreads();
  }
#pragma unroll
  for (int i = 0; i < 4; ++i) {
    int m = m0 + ty * 4 + i;
    float4 o4;
    float* po = (float*)&o4;
#pragma unroll
    for (int j = 0; j < 4; ++j) {
      int n = n0 + tx * 4 + j;
      float v = acc[i][j] + bias1[n] + (bias2 ? bias2[n] : 0.0f);
      if (ACT == 1) v = fmaxf(v, 0.0f);
      po[j] = v;
    }
    *(float4*)&C[(size_t)m * N + n0 + tx * 4] = o4;
  }
}

// ---------------- attention: per (qtile, head, batch) block ----------------
__global__ void attn_kernel(const float* __restrict__ qkv, float* __restrict__ attout) {
  extern __shared__ float sm[];
  float* kl = sm;                        // [256][33]
  float* ql = sm + 256 * 33;             // [32][33]
  float* sc = sm + 256 * 33 + 32 * 33;   // [32][257]
  int qt = blockIdx.x, h = blockIdx.y, b = blockIdx.z;
  int tid = threadIdx.x;  // 256
  {
    int j = tid;
    const float* src = qkv + (size_t)(b * 256 + j) * 768 + 256 + h * 32;
#pragma unroll
    for (int d = 0; d < 32; d += 4) {
      float4 v = *(const float4*)(src + d);
      kl[j * 33 + d] = v.x; kl[j * 33 + d + 1] = v.y; kl[j * 33 + d + 2] = v.z; kl[j * 33 + d + 3] = v.w;
    }
  }
  {
    int i = tid >> 3, d4 = (tid & 7) * 4;
    const float* src = qkv + (size_t)(b * 256 + qt * 32 + i) * 768 + h * 32;
    float4 v = *(const float4*)(src + d4);
    ql[i * 33 + d4] = v.x; ql[i * 33 + d4 + 1] = v.y; ql[i * 33 + d4 + 2] = v.z; ql[i * 33 + d4 + 3] = v.w;
  }
  __syncthreads();
  int i = tid >> 3, c = tid & 7;
  const float scale = 0.17677669529663687f;  // 1/sqrt(32)
  float sv[32];
  float mx = -1e30f;
  for (int jj = 0; jj < 32; ++jj) {
    int j = jj * 8 + c;
    float s = 0.0f;
#pragma unroll
    for (int d = 0; d < 32; ++d) s = fmaf(ql[i * 33 + d], kl[j * 33 + d], s);
    s *= scale;
    sv[jj] = s;
    mx = fmaxf(mx, s);
  }
  mx = fmaxf(mx, __shfl_xor(mx, 1));
  mx = fmaxf(mx, __shfl_xor(mx, 2));
  mx = fmaxf(mx, __shfl_xor(mx, 4));
  float sum = 0.0f;
  for (int jj = 0; jj < 32; ++jj) {
    float p = __expf(sv[jj] - mx);
    sc[i * 257 + jj * 8 + c] = p;
    sum += p;
  }
  sum += __shfl_xor(sum, 1);
  sum += __shfl_xor(sum, 2);
  sum += __shfl_xor(sum, 4);
  float inv = 1.0f / sum;
  __syncthreads();
  float a0 = 0, a1 = 0, a2 = 0, a3 = 0;
  int d0 = c * 4;
  const float* vbase = qkv + 512 + h * 32 + d0;
  for (int j = 0; j < 256; ++j) {
    float p = sc[i * 257 + j];
    float4 v = *(const float4*)(vbase + (size_t)(b * 256 + j) * 768);
    a0 = fmaf(p, v.x, a0); a1 = fmaf(p, v.y, a1); a2 = fmaf(p, v.z, a2); a3 = fmaf(p, v.w, a3);
  }
  int orow = b * 256 + qt * 32 + i;
  float4 o4 = {a0 * inv, a1 * inv, a2 * inv, a3 * inv};
  *(float4*)&attout[(size_t)orow * 256 + h * 32 + d0] = o4;
}

// ---------------- LayerNorm(x + o) in place on x ----------------
__global__ void ln_residual(float* __restrict__ x, const float* __restrict__ o,
                            const float* __restrict__ g, const float* __restrict__ bt) {
  int row = blockIdx.x, tid = threadIdx.x;  // 256 threads
  float e = x[(size_t)row * 256 + tid] + o[(size_t)row * 256 + tid];
  float s = e, q = e * e;
#pragma unroll
  for (int off = 32; off >= 1; off >>= 1) {
    s += __shfl_xor(s, off);
    q += __shfl_xor(q, off);
  }
  __shared__ float ps[4], pq[4];
  int wid = tid >> 6, lane = tid & 63;
  if (lane == 0) { ps[wid] = s; pq[wid] = q; }
  __syncthreads();
  float St = ps[0] + ps[1] + ps[2] + ps[3];
  float Qt = pq[0] + pq[1] + pq[2] + pq[3];
  float mean = St * (1.0f / 256.0f);
  float var = Qt * (1.0f / 256.0f) - mean * mean;
  float y = (e - mean) * rsqrtf(var + 1e-5f) * g[tid] + bt[tid];
  x[(size_t)row * 256 + tid] = y;
}

// ---------------- gather dec_in rows [T,B,H]: row t*8+b ----------------
__global__ void gather_dec_in(const float* __restrict__ enc, const int* __restrict__ ts,
                              float* __restrict__ dec_in) {
  int bx = blockIdx.x;     // t*8 + b
  int t = bx >> 3, b = bx & 7;
  int tid = threadIdx.x;   // 64
  float4 v = {0.0f, 0.0f, 0.0f, 0.0f};
  if (t > 0) {
    int sidx = ts[b * 256 + t - 1];
    v = *(const float4*)&enc[((size_t)(b * 256 + sidx)) * 256 + tid * 4];
  }
  *(float4*)&dec_in[(size_t)bx * 256 + tid * 4] = v;
}

// ---------------- LSTM scan: 1 block per batch, Whh register-resident f16 ----------
// 512 threads; thread t owns gate rows {t, t+512}: t<256 -> (i_t, g_t), t>=256 -> (f_j, o_j).
// Whh cols 0..191 in VGPRs (2 x 96 half2), cols 192..255 in LDS [1024][32] half2 (128 KB).
__global__ __launch_bounds__(512, 2) void lstm_scan(
    const float* __restrict__ Xw, const float* __restrict__ Whh,
    float* __restrict__ dec_out) {
  extern __shared__ char smem[];
  h2* wlds = (h2*)smem;                         // [1024][32] half2 = 128 KB
  h2* hbuf = (h2*)(smem + 131072);              // [2][128] half2 (256 halves each)
  float* ex = (float*)(smem + 131072 + 1024);   // [256] f32
  int b = blockIdx.x;
  int t0 = threadIdx.x;          // 0..511
  int r0 = t0, r1 = t0 + 512;

  h2 w0[96], w1[96];
  {
    const float4* s0 = (const float4*)(Whh + (size_t)r0 * 256);
    const float4* s1 = (const float4*)(Whh + (size_t)r1 * 256);
#pragma unroll
    for (int k = 0; k < 48; ++k) {
      float4 v = s0[k];
      w0[2 * k] = cvt2(v.x, v.y);
      w0[2 * k + 1] = cvt2(v.z, v.w);
    }
#pragma unroll
    for (int k = 0; k < 48; ++k) {
      float4 v = s1[k];
      w1[2 * k] = cvt2(v.x, v.y);
      w1[2 * k + 1] = cvt2(v.z, v.w);
    }
#pragma unroll
    for (int k = 48; k < 64; ++k) {
      float4 v = s0[k];
      wlds[r0 * 32 + 2 * (k - 48)] = cvt2(v.x, v.y);
      wlds[r0 * 32 + 2 * (k - 48) + 1] = cvt2(v.z, v.w);
      float4 u = s1[k];
      wlds[r1 * 32 + 2 * (k - 48)] = cvt2(u.x, u.y);
      wlds[r1 * 32 + 2 * (k - 48) + 1] = cvt2(u.z, u.w);
    }
  }
  if (t0 < 128) { hbuf[t0] = cvt2(0.0f, 0.0f); }  // h buffer 0 = zeros
  float c = 0.0f;
  __syncthreads();

  for (int t = 0; t < 256; ++t) {
    const size_t xof = (size_t)(t * 8 + b) * 1024;
    float xw0 = Xw[xof + r0];
    float xw1 = Xw[xof + r1];
    const uint4* hb = (const uint4*)(hbuf + (size_t)(t & 1) * 128);
    h2 a00 = cvt2(0, 0), a01 = cvt2(0, 0), a02 = cvt2(0, 0), a03 = cvt2(0, 0);
    h2 a10 = cvt2(0, 0), a11 = cvt2(0, 0), a12 = cvt2(0, 0), a13 = cvt2(0, 0);
#pragma unroll
    for (int cb = 0; cb < 24; ++cb) {           // cols 0..191 from registers
      uint4 hv = hb[cb];
      h2 h0 = __builtin_bit_cast(h2, hv.x);
      h2 h1 = __builtin_bit_cast(h2, hv.y);
      h2 hh2 = __builtin_bit_cast(h2, hv.z);
      h2 hh3 = __builtin_bit_cast(h2, hv.w);
      a00 += w0[4 * cb] * h0;     a01 += w0[4 * cb + 1] * h1;
      a02 += w0[4 * cb + 2] * hh2; a03 += w0[4 * cb + 3] * hh3;
      a10 += w1[4 * cb] * h0;     a11 += w1[4 * cb + 1] * h1;
      a12 += w1[4 * cb + 2] * hh2; a13 += w1[4 * cb + 3] * hh3;
    }
    const uint4* wl0 = (const uint4*)(wlds + r0 * 32);
    const uint4* wl1 = (const uint4*)(wlds + r1 * 32);
#pragma unroll
    for (int cb = 0; cb < 8; ++cb) {            // cols 192..255 from LDS
      uint4 hv = hb[24 + cb];
      uint4 wa = wl0[cb];
      uint4 wb = wl1[cb];
      h2 h0 = __builtin_bit_cast(h2, hv.x);
      h2 h1 = __builtin_bit_cast(h2, hv.y);
      h2 hh2 = __builtin_bit_cast(h2, hv.z);
      h2 hh3 = __builtin_bit_cast(h2, hv.w);
      a00 += __builtin_bit_cast(h2, wa.x) * h0;  a01 += __builtin_bit_cast(h2, wa.y) * h1;
      a02 += __builtin_bit_cast(h2, wa.z) * hh2; a03 += __builtin_bit_cast(h2, wa.w) * hh3;
      a10 += __builtin_bit_cast(h2, wb.x) * h0;  a11 += __builtin_bit_cast(h2, wb.y) * h1;
      a12 += __builtin_bit_cast(h2, wb.z) * hh2; a13 += __builtin_bit_cast(h2, wb.w) * hh3;
    }
    h2 sA = (a00 + a01) + (a02 + a03);
    h2 sB = (a10 + a11) + (a12 + a13);
    float g0 = (float)sA.x + (float)sA.y + xw0;
    float g1 = (float)sB.x + (float)sB.y + xw1;
    _Float16* hn = (_Float16*)(hbuf + (size_t)((t + 1) & 1) * 128);
    float sg0 = sigf(g0);
    if (t0 < 256) {
      ex[t0] = sg0 * tanhfast(g1);   // sigma(i)*tanh(g)
    }
    __syncthreads();
    if (t0 >= 256) {
      int j = t0 - 256;
      c = sg0 * c + ex[j];           // sigma(f)*c + sigma(i)*tanh(g)
      float hv = sigf(g1) * tanhfast(c);
      hn[j] = (_Float16)hv;
      dec_out[((size_t)(b * 256 + t)) * 256 + j] = hv;
    }
    __syncthreads();
  }
}

// ---------------- pen transpose: penT[b][h][i] = pen[(b*256+i)][h] ----------------
__global__ void transpose_pen(const float* __restrict__ pen, float* __restrict__ penT) {
  int bx = blockIdx.x;  // b*256 + h
  int b = bx >> 8, h = bx & 255;
  int i = threadIdx.x;  // 256
  penT[(size_t)bx * 256 + i] = pen[((size_t)(b * 256 + i)) * 256 + h];
}

// ---------------- pointer logits ----------------
__global__ void pointer_kernel(const float* __restrict__ pd, const float* __restrict__ penT,
                               const float* __restrict__ vptr, float* __restrict__ out) {
  __shared__ float pdr[256];
  __shared__ float vl[256];
  int bx = blockIdx.x;  // b*256 + t
  int b = bx >> 8;
  int tid = threadIdx.x;  // 256; tid = i (source index)
  pdr[tid] = pd[(size_t)bx * 256 + tid];
  vl[tid] = vptr[tid];
  __syncthreads();
  const float* pT = penT + (size_t)b * 256 * 256;
  float acc = 0.0f;
  for (int h = 0; h < 256; ++h) {
    acc = fmaf(vl[h], tanhfast(pdr[h] + pT[(size_t)h * 256 + tid]), acc);
  }
  out[(size_t)bx * 256 + tid] = acc;
}

extern "C" void kernel_launch(void* const* d_in, const int* in_sizes, int n_in,
                              void* d_out, int out_size, void* d_ws, size_t ws_size,
                              hipStream_t stream) {
  const float* parts = (const float*)d_in[0];
  const int* ts = (const int*)d_in[1];
  const float* Wpe1 = (const float*)d_in[2];
  const float* bpe1 = (const float*)d_in[3];
  const float* Wpe2 = (const float*)d_in[4];
  const float* bpe2 = (const float*)d_in[5];
  const float* pos = (const float*)d_in[6];
  const float* Wqkv = (const float*)d_in[7];
  const float* bqkv = (const float*)d_in[8];
  const float* Wo = (const float*)d_in[9];
  const float* bo = (const float*)d_in[10];
  const float* ln1g = (const float*)d_in[11];
  const float* ln1b = (const float*)d_in[12];
  const float* W1f = (const float*)d_in[13];
  const float* b1f = (const float*)d_in[14];
  const float* W2f = (const float*)d_in[15];
  const float* b2f = (const float*)d_in[16];
  const float* ln2g = (const float*)d_in[17];
  const float* ln2b = (const float*)d_in[18];
  const float* Wih = (const float*)d_in[19];
  const float* Whh = (const float*)d_in[20];
  const float* bih = (const float*)d_in[21];
  const float* bhh = (const float*)d_in[22];
  const float* Wp = (const float*)d_in[23];
  const float* bp = (const float*)d_in[24];
  const float* vptr = (const float*)d_in[25];
  float* out = (float*)d_out;

  float* W = (float*)d_ws;
  float* xbuf = W;                    // [2048,256]
  float* qkvb = W + 524288;           // [2048,768]
  float* attb = W + 2097152;          // [2048,256]
  float* obuf = W + 2621440;          // [2048,256]
  float* ffb  = W + 3145728;          // [2048,512]
  float* dec_in = obuf;
  float* Xw = qkvb;                   // [2048,1024]
  float* dec_out = ffb;
  float* pdb  = W + 3670016;          // [2048,256]
  float* penb = W + 4194304;          // [2048,256]
  float* penTb = W + 4718592;         // [2048,256]

  const int attnLDS = (256 * 33 + 32 * 33 + 32 * 257) * 4;  // 70912 B
  const int scanLDS = 131072 + 1024 + 1024;                 // 133120 B
  hipFuncSetAttribute((const void*)attn_kernel, hipFuncAttributeMaxDynamicSharedMemorySize, attnLDS);
  hipFuncSetAttribute((const void*)lstm_scan, hipFuncAttributeMaxDynamicSharedMemorySize, scanLDS);

  part_encoder<<<2048, 128, 0, stream>>>(parts, Wpe1, bpe1, Wpe2, bpe2, pos, xbuf);
  for (int l = 0; l < 3; ++l) {
    gemm_f32<0><<<dim3(12, 32), 256, 0, stream>>>(xbuf, Wqkv + (size_t)l * 768 * 256,
                                                  bqkv + l * 768, nullptr, qkvb, 768, 256);
    attn_kernel<<<dim3(8, 8, 8), 256, attnLDS, stream>>>(qkvb, attb);
    gemm_f32<0><<<dim3(4, 32), 256, 0, stream>>>(attb, Wo + (size_t)l * 65536,
                                                 bo + l * 256, nullptr, obuf, 256, 256);
    ln_residual<<<2048, 256, 0, stream>>>(xbuf, obuf, ln1g + l * 256, ln1b + l * 256);
    gemm_f32<1><<<dim3(8, 32), 256, 0, stream>>>(xbuf, W1f + (size_t)l * 512 * 256,
                                                 b1f + l * 512, nullptr, ffb, 512, 256);
    gemm_f32<0><<<dim3(4, 32), 256, 0, stream>>>(ffb, W2f + (size_t)l * 256 * 512,
                                                 b2f + l * 256, nullptr, obuf, 256, 512);
    ln_residual<<<2048, 256, 0, stream>>>(xbuf, obuf, ln2g + l * 256, ln2b + l * 256);
  }
  gather_dec_in<<<2048, 64, 0, stream>>>(xbuf, ts, dec_in);
  gemm_f32<0><<<dim3(16, 32), 256, 0, stream>>>(dec_in, Wih, bih, bhh, Xw, 1024, 256);
  lstm_scan<<<8, 512, scanLDS, stream>>>(Xw, Whh, dec_out);
  gemm_f32<0><<<dim3(4, 32), 256, 0, stream>>>(dec_out, Wp, bp, nullptr, pdb, 256, 256);
  gemm_f32<0><<<dim3(4, 32), 256, 0, stream>>>(xbuf, Wp, bp, nullptr, penb, 256, 256);
  transpose_pen<<<2048, 256, 0, stream>>>(penb, penTb);
  pointer_kernel<<<2048, 256, 0, stream>>>(pdb, penTb, vptr, out);
}